// Round 11
// baseline (498.140 us; speedup 1.0000x reference)
//
#include <hip/hip_runtime.h>
#include <hip/hip_bf16.h>
#include <math.h>

#define BB 4
#define HH 8
#define LL 1024
#define DD 32
#define DIMM 256

typedef unsigned short u16;
typedef unsigned int u32;
typedef short bf16x8 __attribute__((ext_vector_type(8)));
typedef float f32x4 __attribute__((ext_vector_type(4)));

__device__ __forceinline__ float bu2f(u16 s) {
  union { unsigned int u; float f; } cv; cv.u = ((unsigned int)s) << 16; return cv.f;
}
__device__ __forceinline__ u16 f2bu(float f) {
  union { float f; unsigned int u; } cv; cv.f = f;
  unsigned int u = cv.u;
  u += 0x7FFFu + ((u >> 16) & 1u);   // round-to-nearest-even
  return (u16)(u >> 16);
}
// compiler-friendly cvt (pairs into v_cvt_pk_bf16_f32)
__device__ __forceinline__ short f2bs(float f) {
  return (short)__bfloat16_as_ushort(__float2bfloat16(f));
}

// ---------------------------------------------------------------- projections
__global__ __launch_bounds__(256) void k_proj(
    const float* __restrict__ x, const float* __restrict__ rx,
    const float* __restrict__ Wq, const float* __restrict__ Wk, const float* __restrict__ Wv,
    u16* __restrict__ xqT_hi, u16* __restrict__ xqT_lo,
    u16* __restrict__ xkT_hi, u16* __restrict__ xkT_lo,
    u16* __restrict__ xvT_hi, u16* __restrict__ xvrT_hi) {
  __shared__ float wq[32][32], wk[32][32], wv[32][32];
  __shared__ float xs[8][32], rxs[8][32];
  __shared__ float tq_[32][9], tk_[32][9], tv_[32][9], tvr_[32][9];
  int tid = threadIdx.x, bid = blockIdx.x;      // grid 4096 = B*H*(L/8)
  int chunk = bid & 127, h = (bid >> 7) & 7, b = bid >> 10;
  int t0 = chunk << 3;
  for (int i = tid; i < 1024; i += 256) {
    int r = i >> 5, c = i & 31;
    wq[r][c] = Wq[i]; wk[r][c] = Wk[i]; wv[r][c] = Wv[i];
  }
  int d = tid & 31, tl = tid >> 5;
  size_t xoff = ((size_t)b * LL + t0 + tl) * DIMM + h * 32 + d;
  xs[tl][d]  = x[xoff];
  rxs[tl][d] = rx[xoff];
  __syncthreads();
  float aq = 0.f, ak = 0.f, av = 0.f, ar = 0.f;
#pragma unroll
  for (int dp = 0; dp < 32; ++dp) {
    float xv_ = xs[tl][dp], rv_ = rxs[tl][dp];
    aq += xv_ * wq[dp][d];
    ak += rv_ * wk[dp][d];
    av += xv_ * wv[dp][d];
    ar += rv_ * wv[dp][d];
  }
  tq_[d][tl] = aq; tk_[d][tl] = ak; tv_[d][tl] = av; tvr_[d][tl] = ar;
  __syncthreads();
  int d2 = tid >> 3, t2 = tid & 7;
  size_t obase = ((size_t)((b * HH + h) * DD + d2)) * LL + t0 + t2;
  {
    float v = tq_[d2][t2]; u16 hi = f2bu(v);
    xqT_hi[obase] = hi; xqT_lo[obase] = f2bu(v - bu2f(hi));
  }
  {
    float v = tk_[d2][t2]; u16 hi = f2bu(v);
    xkT_hi[obase] = hi; xkT_lo[obase] = f2bu(v - bu2f(hi));
  }
  xvT_hi[obase]  = f2bu(tv_[d2][t2]);
  xvrT_hi[obase] = f2bu(tvr_[d2][t2]);
}

// ---------------------------------------------------------------- MFMA GEMM (q/k path) + adj bitmask
template<int PREC, int OUT_SPLIT, int WRITE_BITS>
__global__ __launch_bounds__(256) void k_wmat2(
    const float* __restrict__ wA, const float* __restrict__ wB,
    const u16* __restrict__ sAh, const u16* __restrict__ sAl,
    const u16* __restrict__ sBh, const u16* __restrict__ sBl,
    float* __restrict__ dA, float* __restrict__ dB,
    u16* __restrict__ dAhi, u16* __restrict__ dAlo,
    u16* __restrict__ dBhi, u16* __restrict__ dBlo,
    u32* __restrict__ bits) {
  int tid = threadIdx.x, bid = blockIdx.x;   // grid 1024 = sel(2) x bh(32) x lc(16)
  int sel = bid >> 9;
  const float* w  = sel ? wB : wA;
  const u16* sh   = sel ? sBh : sAh;
  const u16* sl   = sel ? sBl : sAl;
  float* dst      = sel ? dB : dA;
  u16* dhi        = sel ? dBhi : dAhi;
  u16* dlo        = sel ? dBlo : dAlo;
  int b2 = bid & 511;
  int lc = b2 & 15, bh = b2 >> 4;
  int wave = tid >> 6, lane = tid & 63;
  int l0 = (lc << 6) + (wave << 4);          // 16 rows per wave
  int col = lane & 15, g = lane >> 4;
  const float* wrow = w + ((size_t)bh * LL + l0 + col) * LL + (g << 3);
  const u16* b0h = sh + ((size_t)bh * DD + col) * LL + (g << 3);
  const u16* b1h = b0h + 16 * LL;
  const u16* b0l = PREC == 2 ? sl + ((size_t)bh * DD + col) * LL + (g << 3) : nullptr;
  const u16* b1l = PREC == 2 ? b0l + 16 * LL : nullptr;
  unsigned char* bytep = nullptr;
  if (WRITE_BITS && sel == 0)
    bytep = (unsigned char*)(bits + (size_t)bh * 32 * LL + l0 + col) + g;
  f32x4 acc0 = {0.f, 0.f, 0.f, 0.f}, acc1 = {0.f, 0.f, 0.f, 0.f};
#pragma unroll 4
  for (int t0 = 0; t0 < LL; t0 += 32) {
    f32x4 wa = *(const f32x4*)(wrow + t0);
    f32x4 wb = *(const f32x4*)(wrow + t0 + 4);
    bf16x8 whi;
#pragma unroll
    for (int i = 0; i < 4; ++i) {
      whi[i]     = f2bs(wa[i]);
      whi[i + 4] = f2bs(wb[i]);
    }
    if (WRITE_BITS && sel == 0) {
      unsigned int byte = 0;
#pragma unroll
      for (int i = 0; i < 4; ++i) {
        byte |= (wa[i] > 0.f ? 1u : 0u) << i;
        byte |= (wb[i] > 0.f ? 1u : 0u) << (4 + i);
      }
      bytep[(size_t)(t0 >> 5) * (LL * 4)] = (unsigned char)byte;
    }
    bf16x8 s0h = *(const bf16x8*)(b0h + t0);
    bf16x8 s1h = *(const bf16x8*)(b1h + t0);
    acc0 = __builtin_amdgcn_mfma_f32_16x16x32_bf16(whi, s0h, acc0, 0, 0, 0);
    acc1 = __builtin_amdgcn_mfma_f32_16x16x32_bf16(whi, s1h, acc1, 0, 0, 0);
    if (PREC == 2) {
      bf16x8 s0l = *(const bf16x8*)(b0l + t0);
      bf16x8 s1l = *(const bf16x8*)(b1l + t0);
      acc0 = __builtin_amdgcn_mfma_f32_16x16x32_bf16(whi, s0l, acc0, 0, 0, 0);
      acc1 = __builtin_amdgcn_mfma_f32_16x16x32_bf16(whi, s1l, acc1, 0, 0, 0);
    }
  }
#pragma unroll
  for (int i = 0; i < 4; ++i) {
    size_t o = ((size_t)bh * LL + l0 + (g << 2) + i) * DD;
    if (OUT_SPLIT) {
      float v0 = acc0[i]; u16 h0 = f2bu(v0);
      dhi[o + col] = h0; dlo[o + col] = f2bu(v0 - bu2f(h0));
      float v1 = acc1[i]; u16 h1 = f2bu(v1);
      dhi[o + 16 + col] = h1; dlo[o + 16 + col] = f2bu(v1 - bu2f(h1));
    } else {
      dst[o + col] = acc0[i];
      dst[o + 16 + col] = acc1[i];
    }
  }
}

// ---------------------------------------------------------------- 2-pass logits/softmax (M never hits HBM)
// PASS=1: online (max,sum) partials per row per t-chunk -> mpart.
// PASS=2: reduce mpart, recompute identical logits, write A (f32, output),
//         Ab (bf16 copy), colpart2 (lb/wave-level column exp-partials).
template<int PASS>
__global__ __launch_bounds__(256) void k_logits2(
    const u16* __restrict__ qh, const u16* __restrict__ ql,
    const u16* __restrict__ kh, const u16* __restrict__ kl,
    const float* __restrict__ Rm, const u32* __restrict__ bits,
    float2* __restrict__ mpart,
    float* __restrict__ A, u16* __restrict__ Ab, float* __restrict__ colpart2) {
  __shared__ float Rlds[8][8];
  __shared__ float mtile[4][16 * 17];
  __shared__ float2 mstat[8][64];
  int tid = threadIdx.x, bid = blockIdx.x;   // grid 512 = b(4) x tb(8) x lb(16), lb fastest
  int lb = bid & 15, tb = (bid >> 4) & 7, b = bid >> 7;
  int wave = tid >> 6, lane = tid & 63;
  int l0 = (lb << 6) + (wave << 4);
  int tbase = tb << 7;
  int idx16 = lane & 15, g = lane >> 4;
  if (tid < 64) Rlds[tid >> 3][tid & 7] = Rm[tid];
  if (PASS == 2) {
    // reduce mpart (8 tb-partials) -> per-row (max, 1/sum)
    for (int idx = tid; idx < 512; idx += 256) {
      int i = idx >> 6, lr = idx & 63;
      float2 st = make_float2(-INFINITY, 0.f);
      const float2* mp = mpart + ((size_t)(b * HH + i) * 8) * LL + (lb << 6) + lr;
#pragma unroll
      for (int tb2 = 0; tb2 < 8; ++tb2) {
        float2 p = mp[(size_t)tb2 * LL];
        float nm = fmaxf(st.x, p.x);
        if (nm != -INFINITY)
          st = make_float2(nm, st.y * __expf(st.x - nm) + p.y * __expf(p.x - nm));
      }
      mstat[i][lr] = make_float2(st.x, 1.0f / st.y);
    }
  }
  bf16x8 qfh[8], qfl[8];
#pragma unroll
  for (int h = 0; h < 8; ++h) {
    size_t off = ((size_t)(b * HH + h) * LL + l0 + idx16) * DD + (g << 3);
    qfh[h] = *(const bf16x8*)(qh + off);
    qfl[h] = *(const bf16x8*)(ql + off);
  }
  __syncthreads();
  float omx[8][4], osm[8][4];   // PASS1 online stats
  float pmx[8][4], pin[8][4];   // PASS2 row stats
#pragma unroll
  for (int i = 0; i < 8; ++i)
#pragma unroll
    for (int e = 0; e < 4; ++e) {
      if (PASS == 1) { omx[i][e] = -INFINITY; osm[i][e] = 0.f; }
      else {
        float2 st = mstat[i][(wave << 4) + (g << 2) + e];
        pmx[i][e] = st.x; pin[i][e] = st.y;
      }
    }
  int rr_ = lane >> 2, c0 = (lane & 3) << 2;
  for (int tt = 0; tt < 8; ++tt) {
    int t = tbase + (tt << 4);
    f32x4 S[8];
#pragma unroll
    for (int h = 0; h < 8; ++h) {
      size_t koff = ((size_t)(b * HH + h) * LL + t + idx16) * DD + (g << 3);
      bf16x8 bh_ = *(const bf16x8*)(kh + koff);
      bf16x8 bl_ = *(const bf16x8*)(kl + koff);
      f32x4 s = {0.f, 0.f, 0.f, 0.f};
      s = __builtin_amdgcn_mfma_f32_16x16x32_bf16(qfh[h], bh_, s, 0, 0, 0);
      s = __builtin_amdgcn_mfma_f32_16x16x32_bf16(qfl[h], bh_, s, 0, 0, 0);
      s = __builtin_amdgcn_mfma_f32_16x16x32_bf16(qfh[h], bl_, s, 0, 0, 0);
      S[h] = s;
    }
#pragma unroll
    for (int h = 0; h < 8; ++h)
#pragma unroll
      for (int e = 0; e < 4; ++e) {
        float v = S[h][e] * 0.0625f;
        S[h][e] = (v > 0.f) ? v : 0.01f * v;
      }
    int word = t >> 5;
    int bitpos = ((tt & 1) << 4) + idx16;
#pragma unroll
    for (int i = 0; i < 8; ++i) {
      float rr8[8];
#pragma unroll
      for (int h = 0; h < 8; ++h) rr8[h] = Rlds[i][h];
      const u32* bp = bits + ((size_t)(b * HH + i) * 32 + word) * LL + l0 + (g << 2);
      u32 mw0 = bp[0], mw1 = bp[1], mw2 = bp[2], mw3 = bp[3];
      float m_[4];
#pragma unroll
      for (int e = 0; e < 4; ++e) {
        float acc = 0.f;
#pragma unroll
        for (int h = 0; h < 8; ++h) acc += rr8[h] * S[h][e];
        u32 mw = (e == 0) ? mw0 : (e == 1) ? mw1 : (e == 2) ? mw2 : mw3;
        m_[e] = ((mw >> bitpos) & 1u) ? acc : -INFINITY;
      }
      if (PASS == 1) {
#pragma unroll
        for (int e = 0; e < 4; ++e) {
          float m = m_[e];
          if (m > omx[i][e]) {
            osm[i][e] = osm[i][e] * __expf(omx[i][e] - m) + 1.0f;
            omx[i][e] = m;
          } else if (m != -INFINITY) {
            osm[i][e] += __expf(m - omx[i][e]);
          }
        }
      } else {
        float a_[4];
        float cs = 0.f;
#pragma unroll
        for (int e = 0; e < 4; ++e) {
          float a = (m_[e] == -INFINITY) ? 0.f : __expf(m_[e] - pmx[i][e]) * pin[i][e];
          a_[e] = a;
          cs += __expf(a);
        }
        // column partial over this wave's 16 l-rows
        cs += __shfl_xor(cs, 16);
        cs += __shfl_xor(cs, 32);
        if (g == 0)
          colpart2[((((size_t)(b * HH + i) * 16 + lb) * 4 + wave)) * LL + t + idx16] = cs;
        // transpose via per-wave LDS tile -> coalesced A + Ab writes
#pragma unroll
        for (int e = 0; e < 4; ++e)
          mtile[wave][((g << 2) + e) * 17 + idx16] = a_[e];
        float4 v4;
        v4.x = mtile[wave][rr_ * 17 + c0 + 0];
        v4.y = mtile[wave][rr_ * 17 + c0 + 1];
        v4.z = mtile[wave][rr_ * 17 + c0 + 2];
        v4.w = mtile[wave][rr_ * 17 + c0 + 3];
        size_t rowoff = ((size_t)(b * HH + i) * LL + l0 + rr_) * LL + t + c0;
        *(float4*)(A + rowoff) = v4;
        *(short4*)(Ab + rowoff) =
            make_short4(f2bs(v4.x), f2bs(v4.y), f2bs(v4.z), f2bs(v4.w));
      }
    }
  }
  if (PASS == 1) {
    // cross-lane merge over idx16 then write mpart
#pragma unroll
    for (int i = 0; i < 8; ++i)
#pragma unroll
      for (int e = 0; e < 4; ++e) {
        float mx = omx[i][e], sm = osm[i][e];
#pragma unroll
        for (int msk = 1; msk <= 8; msk <<= 1) {
          float mx2 = __shfl_xor(mx, msk);
          float sm2 = __shfl_xor(sm, msk);
          float nm = fmaxf(mx, mx2);
          if (nm == -INFINITY) sm = 0.f;
          else sm = sm * __expf(mx - nm) + sm2 * __expf(mx2 - nm);
          mx = nm;
        }
        if (idx16 == 0)
          mpart[((size_t)(b * HH + i) * 8 + tb) * LL + l0 + (g << 2) + e] =
              make_float2(mx, sm);
      }
  }
}

// ---------------------------------------------------------------- vb GEMM: vb[l,d] = sum_t Ab[l,t]*xv[t,d]
__global__ __launch_bounds__(256) void k_vb(
    const u16* __restrict__ Ab, const u16* __restrict__ xvT, float* __restrict__ vb) {
  int tid = threadIdx.x, bid = blockIdx.x;   // grid 512 = bh(32) x lc(16)
  int lc = bid & 15, bh = bid >> 4;
  int wave = tid >> 6, lane = tid & 63;
  int l0 = (lc << 6) + (wave << 4);
  int idx16 = lane & 15, g = lane >> 4;
  const u16* arow = Ab + ((size_t)bh * LL + l0 + idx16) * LL + (g << 3);
  const u16* b0 = xvT + ((size_t)bh * DD + idx16) * LL + (g << 3);
  const u16* b1 = b0 + 16 * LL;
  f32x4 acc0 = {0.f, 0.f, 0.f, 0.f}, acc1 = {0.f, 0.f, 0.f, 0.f};
#pragma unroll 4
  for (int t0 = 0; t0 < LL; t0 += 32) {
    bf16x8 af = *(const bf16x8*)(arow + t0);
    bf16x8 bb0 = *(const bf16x8*)(b0 + t0);
    bf16x8 bb1 = *(const bf16x8*)(b1 + t0);
    acc0 = __builtin_amdgcn_mfma_f32_16x16x32_bf16(af, bb0, acc0, 0, 0, 0);
    acc1 = __builtin_amdgcn_mfma_f32_16x16x32_bf16(af, bb1, acc1, 0, 0, 0);
  }
#pragma unroll
  for (int e = 0; e < 4; ++e) {
    size_t o = ((size_t)bh * LL + l0 + (g << 2) + e) * DD;
    vb[o + idx16] = acc0[e];
    vb[o + 16 + idx16] = acc1[e];
  }
}

// ---------------------------------------------------------------- Ar[t,l] = exp(Ab[l,t])/colsum[t] + FUSED vr GEMM
__global__ __launch_bounds__(256) void k_arv(
    const u16* __restrict__ Ab, const float* __restrict__ colpart2,
    const u16* __restrict__ xvrT, float* __restrict__ Ar, float* __restrict__ vrb) {
  __shared__ float tile[64][65];
  int tid = threadIdx.x, bid = blockIdx.x;   // grid 512 = bh(32) x tix(16)
  int tix = bid & 15, bh = bid >> 4;
  int t0 = tix << 6;
  int c = tid & 63, w4 = tid >> 6;
  int idx16 = c & 15, g = (c >> 4) & 3;
  float cs = 0.f;
  {
    const float* cp = colpart2 + (size_t)bh * 64 * LL + t0 + c;
#pragma unroll
    for (int chk = 0; chk < 64; ++chk) cs += cp[(size_t)chk * LL];
  }
  float invc = 1.0f / cs;
  f32x4 acc0 = {0.f, 0.f, 0.f, 0.f}, acc1 = {0.f, 0.f, 0.f, 0.f};
  for (int tiy = 0; tiy < 16; ++tiy) {
    int l0 = tiy << 6;
    const u16* Abp = Ab + ((size_t)bh * LL + l0) * LL + t0;
#pragma unroll
    for (int rr = 0; rr < 16; ++rr) {
      int li = (rr << 2) + w4;
      tile[li][c] = __expf(bu2f(Abp[(size_t)li * LL + c])) * invc;
    }
    __syncthreads();
    float* Arb = Ar + ((size_t)bh * LL + t0) * LL + l0;
#pragma unroll
    for (int rr = 0; rr < 16; ++rr) {
      int ti = (rr << 2) + w4;
      Arb[(size_t)ti * LL + c] = tile[c][ti];
    }
#pragma unroll
    for (int kc = 0; kc < 2; ++kc) {
      bf16x8 af;
#pragma unroll
      for (int j = 0; j < 8; ++j)
        af[j] = f2bs(tile[(kc << 5) + (g << 3) + j][(w4 << 4) + idx16]);
      const u16* bp = xvrT + ((size_t)bh * DD + idx16) * LL + l0 + (kc << 5) + (g << 3);
      bf16x8 b0 = *(const bf16x8*)bp;
      bf16x8 b1 = *(const bf16x8*)(bp + 16 * LL);
      acc0 = __builtin_amdgcn_mfma_f32_16x16x32_bf16(af, b0, acc0, 0, 0, 0);
      acc1 = __builtin_amdgcn_mfma_f32_16x16x32_bf16(af, b1, acc1, 0, 0, 0);
    }
    __syncthreads();
  }
#pragma unroll
  for (int e = 0; e < 4; ++e) {
    size_t o = ((size_t)bh * LL + t0 + (w4 << 4) + (g << 2) + e) * DD;
    vrb[o + idx16] = acc0[e];
    vrb[o + 16 + idx16] = acc1[e];
  }
}

// ---------------------------------------------------------------- out = gelu(v_merged) @ Wp, 16 rows/block, both outputs
__global__ __launch_bounds__(256) void k_out2(
    const float* __restrict__ vb, const float* __restrict__ vrb,
    const float* __restrict__ Wp,
    float* __restrict__ out, float* __restrict__ outr) {
  __shared__ float g_s[16 * 256];
  __shared__ float wp_s[32 * 256];
  int tid = threadIdx.x, bid = blockIdx.x;   // grid 512 = sel(2) x b(4) x lt(64)
  int sel = bid >> 8;
  const float* vbuf = sel ? vrb : vb;
  float* o = sel ? outr : out;
  int b2 = bid & 255;
  int lt = b2 & 63, b = b2 >> 6;
  int l0 = lt << 4;
  int h = tid >> 5, dd = tid & 31;
#pragma unroll
  for (int r = 0; r < 16; ++r) {
    float v = vbuf[(((size_t)b * HH + h) * LL + l0 + r) * DD + dd];
    g_s[r * 256 + tid] = 0.5f * v * (1.0f + erff(v * 0.70710678118654752f));
  }
  float acc[16];
#pragma unroll
  for (int r = 0; r < 16; ++r) acc[r] = 0.f;
  for (int jc = 0; jc < 8; ++jc) {
    __syncthreads();
#pragma unroll
    for (int u = 0; u < 8; ++u) {
      int idx = tid + (u << 8);
      int j = idx >> 6, c4 = idx & 63;
      float4 v = *(const float4*)(Wp + (size_t)(jc * 32 + j) * DIMM + (c4 << 2));
      *(float4*)&wp_s[j * 256 + (c4 << 2)] = v;
    }
    __syncthreads();
#pragma unroll
    for (int j = 0; j < 32; ++j) {
      float wv = wp_s[j * 256 + tid];
      int jj = (jc << 5) + j;
#pragma unroll
      for (int r = 0; r < 16; ++r)
        acc[r] += g_s[r * 256 + jj] * wv;
    }
  }
#pragma unroll
  for (int r = 0; r < 16; ++r)
    o[((size_t)b * LL + l0 + r) * DIMM + tid] = acc[r];
}

extern "C" void kernel_launch(void* const* d_in, const int* in_sizes, int n_in,
                              void* d_out, int out_size, void* d_ws, size_t ws_size,
                              hipStream_t stream) {
  const float* x    = (const float*)d_in[0];
  const float* rx   = (const float*)d_in[1];
  const float* adj  = (const float*)d_in[2];
  const float* adjr = (const float*)d_in[3];
  const float* Wq   = (const float*)d_in[4];
  const float* Wk   = (const float*)d_in[5];
  const float* Wv   = (const float*)d_in[6];
  const float* Rm   = (const float*)d_in[7];
  const float* Wp   = (const float*)d_in[8];

  const size_t NE = (size_t)BB * HH * LL * DD;   // 1,048,576 (= B*L*DIM)

  float* out  = (float*)d_out;
  float* outr = out + NE;
  float* A    = outr + NE;
  float* Ar   = A + (size_t)BB * HH * LL * LL;

  // Ar region (33.5M floats, dead until k_arv rewrites all of it):
  u16* q_hi   = (u16*)(Ar);
  u16* q_lo   = q_hi + NE;
  u16* k_hi   = q_lo + NE;
  u16* k_lo   = k_hi + NE;
  u16* xqT_hi = k_lo + NE;
  u16* xqT_lo = xqT_hi + NE;
  u16* xkT_hi = xqT_lo + NE;
  u16* xkT_lo = xkT_hi + NE;                    // ends at Ar + 4*NE floats
  // out region: xvT hi (consumed by k_vb before k_out2 writes out)
  u16* xvT_hi  = (u16*)out;
  // outr region: xvrT hi (consumed by k_arv before k_out2 writes outr)
  u16* xvrT_hi = (u16*)outr;

  // d_ws: ~91 MB (ws is ~1 GB per fill evidence)
  float* wsf      = (float*)d_ws;
  float* vb       = wsf;                         // NE f32
  float* vrb      = wsf + NE;                    // NE f32
  float* colpart2 = wsf + 2 * NE;                // 2*NE f32 (BH*64*1024)
  u32* adjbits    = (u32*)(wsf + 4 * NE);        // NE u32
  float2* mpart   = (float2*)(wsf + 5 * NE);     // BH*8*1024 float2 (2 MB)
  u16* Ab         = (u16*)(wsf + 6 * NE);        // BH*LL*LL bf16 (67 MB)

  k_proj<<<4096, 256, 0, stream>>>(x, rx, Wq, Wk, Wv,
                                   xqT_hi, xqT_lo, xkT_hi, xkT_lo,
                                   xvT_hi, xvrT_hi);
  k_wmat2<2,1,1><<<1024, 256, 0, stream>>>(adj, adjr,
                                           xqT_hi, xqT_lo, xkT_hi, xkT_lo,
                                           nullptr, nullptr,
                                           q_hi, q_lo, k_hi, k_lo, adjbits);
  k_logits2<1><<<512, 256, 0, stream>>>(q_hi, q_lo, k_hi, k_lo, Rm, adjbits,
                                        mpart, nullptr, nullptr, nullptr);
  k_logits2<2><<<512, 256, 0, stream>>>(q_hi, q_lo, k_hi, k_lo, Rm, adjbits,
                                        mpart, A, Ab, colpart2);
  k_vb<<<512, 256, 0, stream>>>(Ab, xvT_hi, vb);
  k_arv<<<512, 256, 0, stream>>>(Ab, colpart2, xvrT_hi, Ar, vrb);
  k_out2<<<512, 256, 0, stream>>>(vb, vrb, Wp, out, outr);
}

// Round 12
// 426.037 us; speedup vs baseline: 1.1692x; 1.1692x over previous
//
#include <hip/hip_runtime.h>
#include <hip/hip_bf16.h>
#include <math.h>

#define BB 4
#define HH 8
#define LL 1024
#define DD 32
#define DIMM 256

typedef unsigned short u16;
typedef unsigned int u32;
typedef short bf16x8 __attribute__((ext_vector_type(8)));
typedef float f32x4 __attribute__((ext_vector_type(4)));

__device__ __forceinline__ float bu2f(u16 s) {
  union { unsigned int u; float f; } cv; cv.u = ((unsigned int)s) << 16; return cv.f;
}
__device__ __forceinline__ u16 f2bu(float f) {
  union { float f; unsigned int u; } cv; cv.f = f;
  unsigned int u = cv.u;
  u += 0x7FFFu + ((u >> 16) & 1u);   // round-to-nearest-even
  return (u16)(u >> 16);
}
// compiler-friendly cvt (pairs into v_cvt_pk_bf16_f32)
__device__ __forceinline__ short f2bs(float f) {
  return (short)__bfloat16_as_ushort(__float2bfloat16(f));
}

// ---------------------------------------------------------------- projections
__global__ __launch_bounds__(256) void k_proj(
    const float* __restrict__ x, const float* __restrict__ rx,
    const float* __restrict__ Wq, const float* __restrict__ Wk, const float* __restrict__ Wv,
    u16* __restrict__ xqT_hi, u16* __restrict__ xqT_lo,
    u16* __restrict__ xkT_hi, u16* __restrict__ xkT_lo,
    u16* __restrict__ xvT_hi, u16* __restrict__ xvrT_hi) {
  __shared__ float wq[32][32], wk[32][32], wv[32][32];
  __shared__ float xs[8][32], rxs[8][32];
  __shared__ float tq_[32][9], tk_[32][9], tv_[32][9], tvr_[32][9];
  int tid = threadIdx.x, bid = blockIdx.x;      // grid 4096 = B*H*(L/8)
  int chunk = bid & 127, h = (bid >> 7) & 7, b = bid >> 10;
  int t0 = chunk << 3;
  for (int i = tid; i < 1024; i += 256) {
    int r = i >> 5, c = i & 31;
    wq[r][c] = Wq[i]; wk[r][c] = Wk[i]; wv[r][c] = Wv[i];
  }
  int d = tid & 31, tl = tid >> 5;
  size_t xoff = ((size_t)b * LL + t0 + tl) * DIMM + h * 32 + d;
  xs[tl][d]  = x[xoff];
  rxs[tl][d] = rx[xoff];
  __syncthreads();
  float aq = 0.f, ak = 0.f, av = 0.f, ar = 0.f;
#pragma unroll
  for (int dp = 0; dp < 32; ++dp) {
    float xv_ = xs[tl][dp], rv_ = rxs[tl][dp];
    aq += xv_ * wq[dp][d];
    ak += rv_ * wk[dp][d];
    av += xv_ * wv[dp][d];
    ar += rv_ * wv[dp][d];
  }
  tq_[d][tl] = aq; tk_[d][tl] = ak; tv_[d][tl] = av; tvr_[d][tl] = ar;
  __syncthreads();
  int d2 = tid >> 3, t2 = tid & 7;
  size_t obase = ((size_t)((b * HH + h) * DD + d2)) * LL + t0 + t2;
  {
    float v = tq_[d2][t2]; u16 hi = f2bu(v);
    xqT_hi[obase] = hi; xqT_lo[obase] = f2bu(v - bu2f(hi));
  }
  {
    float v = tk_[d2][t2]; u16 hi = f2bu(v);
    xkT_hi[obase] = hi; xkT_lo[obase] = f2bu(v - bu2f(hi));
  }
  xvT_hi[obase]  = f2bu(tv_[d2][t2]);
  xvrT_hi[obase] = f2bu(tvr_[d2][t2]);
}

// ---------------------------------------------------------------- MFMA GEMM (q/k path) + adj bitmask
template<int PREC, int OUT_SPLIT, int WRITE_BITS>
__global__ __launch_bounds__(256) void k_wmat2(
    const float* __restrict__ wA, const float* __restrict__ wB,
    const u16* __restrict__ sAh, const u16* __restrict__ sAl,
    const u16* __restrict__ sBh, const u16* __restrict__ sBl,
    float* __restrict__ dA, float* __restrict__ dB,
    u16* __restrict__ dAhi, u16* __restrict__ dAlo,
    u16* __restrict__ dBhi, u16* __restrict__ dBlo,
    u32* __restrict__ bits) {
  int tid = threadIdx.x, bid = blockIdx.x;   // grid 1024 = sel(2) x bh(32) x lc(16)
  int sel = bid >> 9;
  const float* w  = sel ? wB : wA;
  const u16* sh   = sel ? sBh : sAh;
  const u16* sl   = sel ? sBl : sAl;
  float* dst      = sel ? dB : dA;
  u16* dhi        = sel ? dBhi : dAhi;
  u16* dlo        = sel ? dBlo : dAlo;
  int b2 = bid & 511;
  int lc = b2 & 15, bh = b2 >> 4;
  int wave = tid >> 6, lane = tid & 63;
  int l0 = (lc << 6) + (wave << 4);          // 16 rows per wave
  int col = lane & 15, g = lane >> 4;
  const float* wrow = w + ((size_t)bh * LL + l0 + col) * LL + (g << 3);
  const u16* b0h = sh + ((size_t)bh * DD + col) * LL + (g << 3);
  const u16* b1h = b0h + 16 * LL;
  const u16* b0l = PREC == 2 ? sl + ((size_t)bh * DD + col) * LL + (g << 3) : nullptr;
  const u16* b1l = PREC == 2 ? b0l + 16 * LL : nullptr;
  unsigned char* bytep = nullptr;
  if (WRITE_BITS && sel == 0)
    bytep = (unsigned char*)(bits + (size_t)bh * 32 * LL + l0 + col) + g;
  f32x4 acc0 = {0.f, 0.f, 0.f, 0.f}, acc1 = {0.f, 0.f, 0.f, 0.f};
#pragma unroll 4
  for (int t0 = 0; t0 < LL; t0 += 32) {
    f32x4 wa = *(const f32x4*)(wrow + t0);
    f32x4 wb = *(const f32x4*)(wrow + t0 + 4);
    bf16x8 whi;
#pragma unroll
    for (int i = 0; i < 4; ++i) {
      whi[i]     = f2bs(wa[i]);
      whi[i + 4] = f2bs(wb[i]);
    }
    if (WRITE_BITS && sel == 0) {
      unsigned int byte = 0;
#pragma unroll
      for (int i = 0; i < 4; ++i) {
        byte |= (wa[i] > 0.f ? 1u : 0u) << i;
        byte |= (wb[i] > 0.f ? 1u : 0u) << (4 + i);
      }
      bytep[(size_t)(t0 >> 5) * (LL * 4)] = (unsigned char)byte;
    }
    bf16x8 s0h = *(const bf16x8*)(b0h + t0);
    bf16x8 s1h = *(const bf16x8*)(b1h + t0);
    acc0 = __builtin_amdgcn_mfma_f32_16x16x32_bf16(whi, s0h, acc0, 0, 0, 0);
    acc1 = __builtin_amdgcn_mfma_f32_16x16x32_bf16(whi, s1h, acc1, 0, 0, 0);
    if (PREC == 2) {
      bf16x8 s0l = *(const bf16x8*)(b0l + t0);
      bf16x8 s1l = *(const bf16x8*)(b1l + t0);
      acc0 = __builtin_amdgcn_mfma_f32_16x16x32_bf16(whi, s0l, acc0, 0, 0, 0);
      acc1 = __builtin_amdgcn_mfma_f32_16x16x32_bf16(whi, s1l, acc1, 0, 0, 0);
    }
  }
  // C/D: col=lane&15, row=(lane>>4)*4+reg  [m89-verified, r4-r10 passed]
#pragma unroll
  for (int i = 0; i < 4; ++i) {
    size_t o = ((size_t)bh * LL + l0 + (g << 2) + i) * DD;
    if (OUT_SPLIT) {
      float v0 = acc0[i]; u16 h0 = f2bu(v0);
      dhi[o + col] = h0; dlo[o + col] = f2bu(v0 - bu2f(h0));
      float v1 = acc1[i]; u16 h1 = f2bu(v1);
      dhi[o + 16 + col] = h1; dlo[o + 16 + col] = f2bu(v1 - bu2f(h1));
    } else {
      dst[o + col] = acc0[i];
      dst[o + 16 + col] = acc1[i];
    }
  }
}

// ---------------------------------------------------------------- logits via MFMA: S=q·k^T/16, lrelu, R-mix, mask -> M
// lb fastest: consecutive blocks share the same k-slice (L2 locality).
__global__ __launch_bounds__(256) void k_logits_mfma(
    const u16* __restrict__ qh, const u16* __restrict__ ql,
    const u16* __restrict__ kh, const u16* __restrict__ kl,
    const float* __restrict__ Rm, const u32* __restrict__ bits,
    float* __restrict__ M) {
  __shared__ float Rlds[8][8];
  __shared__ float mtile[4][16 * 17];
  int tid = threadIdx.x, bid = blockIdx.x;
  int lb = bid & 15, tb = (bid >> 4) & 7, b = bid >> 7;   // lb fastest
  int wave = tid >> 6, lane = tid & 63;
  int l0 = (lb << 6) + (wave << 4);
  int tbase = tb << 7;
  int idx16 = lane & 15, g = lane >> 4;
  if (tid < 64) Rlds[tid >> 3][tid & 7] = Rm[tid];
  bf16x8 qfh[8], qfl[8];
#pragma unroll
  for (int h = 0; h < 8; ++h) {
    size_t off = ((size_t)(b * HH + h) * LL + l0 + idx16) * DD + (g << 3);
    qfh[h] = *(const bf16x8*)(qh + off);
    qfl[h] = *(const bf16x8*)(ql + off);
  }
  __syncthreads();
  int rr_ = lane >> 2, c0 = (lane & 3) << 2;   // LDS-read / global-write mapping
  for (int tt = 0; tt < 8; ++tt) {
    int t = tbase + (tt << 4);
    f32x4 S[8];
#pragma unroll
    for (int h = 0; h < 8; ++h) {
      size_t koff = ((size_t)(b * HH + h) * LL + t + idx16) * DD + (g << 3);
      bf16x8 bh_ = *(const bf16x8*)(kh + koff);
      bf16x8 bl_ = *(const bf16x8*)(kl + koff);
      f32x4 s = {0.f, 0.f, 0.f, 0.f};
      s = __builtin_amdgcn_mfma_f32_16x16x32_bf16(qfh[h], bh_, s, 0, 0, 0);
      s = __builtin_amdgcn_mfma_f32_16x16x32_bf16(qfl[h], bh_, s, 0, 0, 0);
      s = __builtin_amdgcn_mfma_f32_16x16x32_bf16(qfh[h], bl_, s, 0, 0, 0);
      S[h] = s;
    }
#pragma unroll
    for (int h = 0; h < 8; ++h)
#pragma unroll
      for (int e = 0; e < 4; ++e) {
        float v = S[h][e] * 0.0625f;
        S[h][e] = (v > 0.f) ? v : 0.01f * v;
      }
    int word = t >> 5;                 // idx16<16 never crosses a 32-bit word
    int bitpos = ((tt & 1) << 4) + idx16;
#pragma unroll
    for (int i = 0; i < 8; ++i) {
      float rr8[8];
#pragma unroll
      for (int h = 0; h < 8; ++h) rr8[h] = Rlds[i][h];
      const u32* bp = bits + ((size_t)(b * HH + i) * 32 + word) * LL + l0 + (g << 2);
      u32 mw0 = bp[0], mw1 = bp[1], mw2 = bp[2], mw3 = bp[3];
      float m_[4];
#pragma unroll
      for (int e = 0; e < 4; ++e) {
        float acc = 0.f;
#pragma unroll
        for (int h = 0; h < 8; ++h) acc += rr8[h] * S[h][e];
        u32 mw = (e == 0) ? mw0 : (e == 1) ? mw1 : (e == 2) ? mw2 : mw3;
        m_[e] = ((mw >> bitpos) & 1u) ? acc : -INFINITY;
      }
#pragma unroll
      for (int e = 0; e < 4; ++e)
        mtile[wave][((g << 2) + e) * 17 + idx16] = m_[e];
      float4 v4;
      v4.x = mtile[wave][rr_ * 17 + c0 + 0];
      v4.y = mtile[wave][rr_ * 17 + c0 + 1];
      v4.z = mtile[wave][rr_ * 17 + c0 + 2];
      v4.w = mtile[wave][rr_ * 17 + c0 + 3];
      *(float4*)(M + ((size_t)(b * HH + i) * LL + l0 + rr_) * LL + t + c0) = v4;
    }
  }
}

// ---------------------------------------------------------------- row softmax M->A in place + colpart + FUSED vb GEMM
__global__ __launch_bounds__(256) void k_norm2v(
    float* __restrict__ A, const u16* __restrict__ xvT,
    float* __restrict__ colpart, float* __restrict__ vb) {
  __shared__ u16 Ast[32][1032];   // 66 KB; stride 1032 -> b128 frag reads 2-way max
  int tid = threadIdx.x, bid = blockIdx.x;   // grid 1024 = bh(32) x ch(32)
  int ch = bid & 31, bh = bid >> 5;
  int wave = tid >> 6, lane = tid & 63;
  float4 colA[4];
#pragma unroll
  for (int j = 0; j < 4; ++j) colA[j] = make_float4(0.f, 0.f, 0.f, 0.f);
  for (int rr = 0; rr < 8; ++rr) {
    int row = (rr << 2) + wave;                  // 0..31 within block
    int l = (ch << 5) + row;
    float4* Ap = (float4*)(A + ((size_t)bh * LL + l) * LL);
    float4 v[4];
#pragma unroll
    for (int j = 0; j < 4; ++j) v[j] = Ap[lane + (j << 6)];
    float mx = -INFINITY;
#pragma unroll
    for (int j = 0; j < 4; ++j)
      mx = fmaxf(mx, fmaxf(fmaxf(v[j].x, v[j].y), fmaxf(v[j].z, v[j].w)));
#pragma unroll
    for (int o = 32; o > 0; o >>= 1) mx = fmaxf(mx, __shfl_xor(mx, o, 64));
    float sm = 0.f;
#pragma unroll
    for (int j = 0; j < 4; ++j) {
      v[j].x = __expf(v[j].x - mx); v[j].y = __expf(v[j].y - mx);
      v[j].z = __expf(v[j].z - mx); v[j].w = __expf(v[j].w - mx);
      sm += v[j].x + v[j].y + v[j].z + v[j].w;
    }
#pragma unroll
    for (int o = 32; o > 0; o >>= 1) sm += __shfl_xor(sm, o, 64);
    float inv = 1.0f / sm;
#pragma unroll
    for (int j = 0; j < 4; ++j) {
      v[j].x *= inv; v[j].y *= inv; v[j].z *= inv; v[j].w *= inv;
      colA[j].x += __expf(v[j].x); colA[j].y += __expf(v[j].y);
      colA[j].z += __expf(v[j].z); colA[j].w += __expf(v[j].w);
      Ap[lane + (j << 6)] = v[j];
      int c4 = (lane + (j << 6)) << 2;
      *(short4*)&Ast[row][c4] =
          make_short4(f2bs(v[j].x), f2bs(v[j].y), f2bs(v[j].z), f2bs(v[j].w));
    }
  }
  __syncthreads();
  // GEMM: wave = (Mt, Nt); C-frag 16x16; K = 1024
  int idx16 = lane & 15, g = lane >> 4;
  int Mt = wave >> 1, Nt = wave & 1;
  f32x4 acc = {0.f, 0.f, 0.f, 0.f};
  const u16* bbase = xvT + ((size_t)bh * DD + Nt * 16 + idx16) * LL;
#pragma unroll 4
  for (int kc = 0; kc < 32; ++kc) {
    bf16x8 af = *(const bf16x8*)&Ast[(Mt << 4) + idx16][(kc << 5) + (g << 3)];
    bf16x8 bfr = *(const bf16x8*)(bbase + (kc << 5) + (g << 3));
    acc = __builtin_amdgcn_mfma_f32_16x16x32_bf16(af, bfr, acc, 0, 0, 0);
  }
#pragma unroll
  for (int e = 0; e < 4; ++e)
    vb[((size_t)bh * LL + (ch << 5) + (Mt << 4) + (g << 2) + e) * DD + Nt * 16 + idx16] = acc[e];
  __syncthreads();
  // colpart via reused LDS
  float* cf = (float*)&Ast[0][0];
#pragma unroll
  for (int j = 0; j < 4; ++j)
    *(float4*)&cf[wave * 1024 + (j << 8) + (lane << 2)] = colA[j];
  __syncthreads();
  float4 s = make_float4(0.f, 0.f, 0.f, 0.f);
#pragma unroll
  for (int w = 0; w < 4; ++w) {
    float4 t = *(const float4*)&cf[w * 1024 + (tid << 2)];
    s.x += t.x; s.y += t.y; s.z += t.z; s.w += t.w;
  }
  ((float4*)(colpart + ((size_t)bh * 32 + ch) * LL))[tid] = s;
}

// ---------------------------------------------------------------- Ar[t,l] = exp(A[l,t])/colsum[t] + FUSED vr GEMM
// colsum inline from colpart; DOUBLE-BUFFERED tile -> 1 barrier per l-chunk.
__global__ __launch_bounds__(256) void k_arv(
    const float* __restrict__ A, const float* __restrict__ colpart,
    const u16* __restrict__ xvrT, float* __restrict__ Ar, float* __restrict__ vrb) {
  __shared__ float tile[2][64][65];
  int tid = threadIdx.x, bid = blockIdx.x;   // grid 512 = bh(32) x tix(16)
  int tix = bid & 15, bh = bid >> 4;
  int t0 = tix << 6;
  int c = tid & 63, w4 = tid >> 6;
  int idx16 = c & 15, g = (c >> 4) & 3;
  float cs = 0.f;
  {
    const float* cp = colpart + (size_t)bh * 32 * LL + t0 + c;
#pragma unroll
    for (int chk = 0; chk < 32; ++chk) cs += cp[chk * LL];
  }
  float invc = 1.0f / cs;
  f32x4 acc0 = {0.f, 0.f, 0.f, 0.f}, acc1 = {0.f, 0.f, 0.f, 0.f};
  // prologue: stage chunk 0 into buf 0
  {
    const float* Ab = A + ((size_t)bh * LL + 0) * LL + t0;
#pragma unroll
    for (int rr = 0; rr < 16; ++rr) {
      int li = (rr << 2) + w4;
      tile[0][li][c] = __expf(Ab[(size_t)li * LL + c]) * invc;
    }
  }
  for (int tiy = 0; tiy < 16; ++tiy) {
    int cur = tiy & 1;
    __syncthreads();                       // buf[cur] staged; buf[cur^1] free
    // stage NEXT chunk into the other buffer (overlaps with consume below)
    if (tiy < 15) {
      int l0n = (tiy + 1) << 6;
      const float* Ab = A + ((size_t)bh * LL + l0n) * LL + t0;
#pragma unroll
      for (int rr = 0; rr < 16; ++rr) {
        int li = (rr << 2) + w4;
        tile[cur ^ 1][li][c] = __expf(Ab[(size_t)li * LL + c]) * invc;
      }
    }
    int l0 = tiy << 6;
    // Ar write (transposed, coalesced); tile[c][ti] carries 1/colsum[t0+ti]
    float* Arb = Ar + ((size_t)bh * LL + t0) * LL + l0;
#pragma unroll
    for (int rr = 0; rr < 16; ++rr) {
      int ti = (rr << 2) + w4;
      Arb[(size_t)ti * LL + c] = tile[cur][c][ti];
    }
    // vr MFMA: A-op[m=t][k=l] from tile (scalar ds reads, 2-way banks)
#pragma unroll
    for (int kc = 0; kc < 2; ++kc) {
      bf16x8 af;
#pragma unroll
      for (int j = 0; j < 8; ++j)
        af[j] = f2bs(tile[cur][(kc << 5) + (g << 3) + j][(w4 << 4) + idx16]);
      const u16* bp = xvrT + ((size_t)bh * DD + idx16) * LL + l0 + (kc << 5) + (g << 3);
      bf16x8 b0 = *(const bf16x8*)bp;
      bf16x8 b1 = *(const bf16x8*)(bp + 16 * LL);
      acc0 = __builtin_amdgcn_mfma_f32_16x16x32_bf16(af, b0, acc0, 0, 0, 0);
      acc1 = __builtin_amdgcn_mfma_f32_16x16x32_bf16(af, b1, acc1, 0, 0, 0);
    }
  }
#pragma unroll
  for (int e = 0; e < 4; ++e) {
    size_t o = ((size_t)bh * LL + t0 + (w4 << 4) + (g << 2) + e) * DD;
    vrb[o + idx16] = acc0[e];
    vrb[o + 16 + idx16] = acc1[e];
  }
}

// ---------------------------------------------------------------- out = gelu(v_merged) @ Wp, 16 rows/block, both outputs
__global__ __launch_bounds__(256) void k_out2(
    const float* __restrict__ vb, const float* __restrict__ vrb,
    const float* __restrict__ Wp,
    float* __restrict__ out, float* __restrict__ outr) {
  __shared__ float g_s[16 * 256];
  __shared__ float wp_s[32 * 256];
  int tid = threadIdx.x, bid = blockIdx.x;   // grid 512 = sel(2) x b(4) x lt(64)
  int sel = bid >> 8;
  const float* vbuf = sel ? vrb : vb;
  float* o = sel ? outr : out;
  int b2 = bid & 255;
  int lt = b2 & 63, b = b2 >> 6;
  int l0 = lt << 4;
  int h = tid >> 5, dd = tid & 31;
#pragma unroll
  for (int r = 0; r < 16; ++r) {
    float v = vbuf[(((size_t)b * HH + h) * LL + l0 + r) * DD + dd];
    g_s[r * 256 + tid] = 0.5f * v * (1.0f + erff(v * 0.70710678118654752f));
  }
  float acc[16];
#pragma unroll
  for (int r = 0; r < 16; ++r) acc[r] = 0.f;
  for (int jc = 0; jc < 8; ++jc) {
    __syncthreads();
#pragma unroll
    for (int u = 0; u < 8; ++u) {
      int idx = tid + (u << 8);
      int j = idx >> 6, c4 = idx & 63;
      float4 v = *(const float4*)(Wp + (size_t)(jc * 32 + j) * DIMM + (c4 << 2));
      *(float4*)&wp_s[j * 256 + (c4 << 2)] = v;
    }
    __syncthreads();
#pragma unroll
    for (int j = 0; j < 32; ++j) {
      float wv = wp_s[j * 256 + tid];
      int jj = (jc << 5) + j;
#pragma unroll
      for (int r = 0; r < 16; ++r)
        acc[r] += g_s[r * 256 + jj] * wv;
    }
  }
#pragma unroll
  for (int r = 0; r < 16; ++r)
    o[((size_t)b * LL + l0 + r) * DIMM + tid] = acc[r];
}

extern "C" void kernel_launch(void* const* d_in, const int* in_sizes, int n_in,
                              void* d_out, int out_size, void* d_ws, size_t ws_size,
                              hipStream_t stream) {
  const float* x    = (const float*)d_in[0];
  const float* rx   = (const float*)d_in[1];
  const float* adj  = (const float*)d_in[2];
  const float* adjr = (const float*)d_in[3];
  const float* Wq   = (const float*)d_in[4];
  const float* Wk   = (const float*)d_in[5];
  const float* Wv   = (const float*)d_in[6];
  const float* Rm   = (const float*)d_in[7];
  const float* Wp   = (const float*)d_in[8];

  const size_t NE = (size_t)BB * HH * LL * DD;   // 1,048,576 (= B*L*DIM)

  float* out  = (float*)d_out;
  float* outr = out + NE;
  float* A    = outr + NE;
  float* Ar   = A + (size_t)BB * HH * LL * LL;

  // Ar region (33.5M floats, dead until k_arv rewrites all of it):
  u16* q_hi   = (u16*)(Ar);
  u16* q_lo   = q_hi + NE;
  u16* k_hi   = q_lo + NE;
  u16* k_lo   = k_hi + NE;
  u16* xqT_hi = k_lo + NE;
  u16* xqT_lo = xqT_hi + NE;
  u16* xkT_hi = xqT_lo + NE;
  u16* xkT_lo = xkT_hi + NE;                    // ends at Ar + 4*NE floats
  // out region: xvT hi (consumed by k_norm2v before k_out2 writes out)
  u16* xvT_hi  = (u16*)out;
  // outr region: xvrT hi (consumed by k_arv before k_out2 writes outr)
  u16* xvrT_hi = (u16*)outr;

  // d_ws: 16.3 MB (colpart here: k_arv reads it while writing the Ar region)
  float* wsf    = (float*)d_ws;
  float* vb     = wsf;                       // NE f32
  float* vrb    = wsf + NE;                  // NE f32
  float* colpart = wsf + 2 * NE;             // NE f32
  u32* adjbits  = (u32*)(wsf + 3 * NE);      // BH*32*1024 u32 = 4 MB

  k_proj<<<4096, 256, 0, stream>>>(x, rx, Wq, Wk, Wv,
                                   xqT_hi, xqT_lo, xkT_hi, xkT_lo,
                                   xvT_hi, xvrT_hi);
  k_wmat2<2,1,1><<<1024, 256, 0, stream>>>(adj, adjr,
                                           xqT_hi, xqT_lo, xkT_hi, xkT_lo,
                                           nullptr, nullptr,
                                           q_hi, q_lo, k_hi, k_lo, adjbits);
  k_logits_mfma<<<512, 256, 0, stream>>>(q_hi, q_lo, k_hi, k_lo, Rm, adjbits, A);
  k_norm2v<<<1024, 256, 0, stream>>>(A, xvT_hi, colpart, vb);
  k_arv<<<512, 256, 0, stream>>>(A, colpart, xvrT_hi, Ar, vrb);
  k_out2<<<512, 256, 0, stream>>>(vb, vrb, Wp, out, outr);
}

// Round 13
// 381.430 us; speedup vs baseline: 1.3060x; 1.1169x over previous
//
#include <hip/hip_runtime.h>
#include <hip/hip_bf16.h>
#include <math.h>

#define BB 4
#define HH 8
#define LL 1024
#define DD 32
#define DIMM 256

typedef unsigned short u16;
typedef unsigned int u32;
typedef short bf16x8 __attribute__((ext_vector_type(8)));
typedef float f32x4 __attribute__((ext_vector_type(4)));

__device__ __forceinline__ float bu2f(u16 s) {
  union { unsigned int u; float f; } cv; cv.u = ((unsigned int)s) << 16; return cv.f;
}
__device__ __forceinline__ u16 f2bu(float f) {
  union { float f; unsigned int u; } cv; cv.f = f;
  unsigned int u = cv.u;
  u += 0x7FFFu + ((u >> 16) & 1u);   // round-to-nearest-even
  return (u16)(u >> 16);
}
// compiler-friendly cvt (pairs into v_cvt_pk_bf16_f32)
__device__ __forceinline__ short f2bs(float f) {
  return (short)__bfloat16_as_ushort(__float2bfloat16(f));
}

// ---------------------------------------------------------------- projections
__global__ __launch_bounds__(256) void k_proj(
    const float* __restrict__ x, const float* __restrict__ rx,
    const float* __restrict__ Wq, const float* __restrict__ Wk, const float* __restrict__ Wv,
    u16* __restrict__ xqT_hi, u16* __restrict__ xqT_lo,
    u16* __restrict__ xkT_hi, u16* __restrict__ xkT_lo,
    u16* __restrict__ xvT_hi, u16* __restrict__ xvrT_hi) {
  __shared__ float wq[32][32], wk[32][32], wv[32][32];
  __shared__ float xs[8][32], rxs[8][32];
  __shared__ float tq_[32][9], tk_[32][9], tv_[32][9], tvr_[32][9];
  int tid = threadIdx.x, bid = blockIdx.x;      // grid 4096 = B*H*(L/8)
  int chunk = bid & 127, h = (bid >> 7) & 7, b = bid >> 10;
  int t0 = chunk << 3;
  for (int i = tid; i < 1024; i += 256) {
    int r = i >> 5, c = i & 31;
    wq[r][c] = Wq[i]; wk[r][c] = Wk[i]; wv[r][c] = Wv[i];
  }
  int d = tid & 31, tl = tid >> 5;
  size_t xoff = ((size_t)b * LL + t0 + tl) * DIMM + h * 32 + d;
  xs[tl][d]  = x[xoff];
  rxs[tl][d] = rx[xoff];
  __syncthreads();
  float aq = 0.f, ak = 0.f, av = 0.f, ar = 0.f;
#pragma unroll
  for (int dp = 0; dp < 32; ++dp) {
    float xv_ = xs[tl][dp], rv_ = rxs[tl][dp];
    aq += xv_ * wq[dp][d];
    ak += rv_ * wk[dp][d];
    av += xv_ * wv[dp][d];
    ar += rv_ * wv[dp][d];
  }
  tq_[d][tl] = aq; tk_[d][tl] = ak; tv_[d][tl] = av; tvr_[d][tl] = ar;
  __syncthreads();
  int d2 = tid >> 3, t2 = tid & 7;
  size_t obase = ((size_t)((b * HH + h) * DD + d2)) * LL + t0 + t2;
  {
    float v = tq_[d2][t2]; u16 hi = f2bu(v);
    xqT_hi[obase] = hi; xqT_lo[obase] = f2bu(v - bu2f(hi));
  }
  {
    float v = tk_[d2][t2]; u16 hi = f2bu(v);
    xkT_hi[obase] = hi; xkT_lo[obase] = f2bu(v - bu2f(hi));
  }
  xvT_hi[obase]  = f2bu(tv_[d2][t2]);
  xvrT_hi[obase] = f2bu(tvr_[d2][t2]);
}

// ---------------------------------------------------------------- MFMA GEMM (q/k path) + adj bitmask
template<int PREC, int OUT_SPLIT, int WRITE_BITS>
__global__ __launch_bounds__(256) void k_wmat2(
    const float* __restrict__ wA, const float* __restrict__ wB,
    const u16* __restrict__ sAh, const u16* __restrict__ sAl,
    const u16* __restrict__ sBh, const u16* __restrict__ sBl,
    float* __restrict__ dA, float* __restrict__ dB,
    u16* __restrict__ dAhi, u16* __restrict__ dAlo,
    u16* __restrict__ dBhi, u16* __restrict__ dBlo,
    u32* __restrict__ bits) {
  int tid = threadIdx.x, bid = blockIdx.x;   // grid 1024 = sel(2) x bh(32) x lc(16)
  int sel = bid >> 9;
  const float* w  = sel ? wB : wA;
  const u16* sh   = sel ? sBh : sAh;
  const u16* sl   = sel ? sBl : sAl;
  float* dst      = sel ? dB : dA;
  u16* dhi        = sel ? dBhi : dAhi;
  u16* dlo        = sel ? dBlo : dAlo;
  int b2 = bid & 511;
  int lc = b2 & 15, bh = b2 >> 4;
  int wave = tid >> 6, lane = tid & 63;
  int l0 = (lc << 6) + (wave << 4);          // 16 rows per wave
  int col = lane & 15, g = lane >> 4;
  const float* wrow = w + ((size_t)bh * LL + l0 + col) * LL + (g << 3);
  const u16* b0h = sh + ((size_t)bh * DD + col) * LL + (g << 3);
  const u16* b1h = b0h + 16 * LL;
  const u16* b0l = PREC == 2 ? sl + ((size_t)bh * DD + col) * LL + (g << 3) : nullptr;
  const u16* b1l = PREC == 2 ? b0l + 16 * LL : nullptr;
  unsigned char* bytep = nullptr;
  if (WRITE_BITS && sel == 0)
    bytep = (unsigned char*)(bits + (size_t)bh * 32 * LL + l0 + col) + g;
  f32x4 acc0 = {0.f, 0.f, 0.f, 0.f}, acc1 = {0.f, 0.f, 0.f, 0.f};
#pragma unroll 4
  for (int t0 = 0; t0 < LL; t0 += 32) {
    f32x4 wa = *(const f32x4*)(wrow + t0);
    f32x4 wb = *(const f32x4*)(wrow + t0 + 4);
    bf16x8 whi;
#pragma unroll
    for (int i = 0; i < 4; ++i) {
      whi[i]     = f2bs(wa[i]);
      whi[i + 4] = f2bs(wb[i]);
    }
    if (WRITE_BITS && sel == 0) {
      unsigned int byte = 0;
#pragma unroll
      for (int i = 0; i < 4; ++i) {
        byte |= (wa[i] > 0.f ? 1u : 0u) << i;
        byte |= (wb[i] > 0.f ? 1u : 0u) << (4 + i);
      }
      bytep[(size_t)(t0 >> 5) * (LL * 4)] = (unsigned char)byte;
    }
    bf16x8 s0h = *(const bf16x8*)(b0h + t0);
    bf16x8 s1h = *(const bf16x8*)(b1h + t0);
    acc0 = __builtin_amdgcn_mfma_f32_16x16x32_bf16(whi, s0h, acc0, 0, 0, 0);
    acc1 = __builtin_amdgcn_mfma_f32_16x16x32_bf16(whi, s1h, acc1, 0, 0, 0);
    if (PREC == 2) {
      bf16x8 s0l = *(const bf16x8*)(b0l + t0);
      bf16x8 s1l = *(const bf16x8*)(b1l + t0);
      acc0 = __builtin_amdgcn_mfma_f32_16x16x32_bf16(whi, s0l, acc0, 0, 0, 0);
      acc1 = __builtin_amdgcn_mfma_f32_16x16x32_bf16(whi, s1l, acc1, 0, 0, 0);
    }
  }
  // C/D: col=lane&15, row=(lane>>4)*4+reg  [m89-verified, r4-r12 passed]
#pragma unroll
  for (int i = 0; i < 4; ++i) {
    size_t o = ((size_t)bh * LL + l0 + (g << 2) + i) * DD;
    if (OUT_SPLIT) {
      float v0 = acc0[i]; u16 h0 = f2bu(v0);
      dhi[o + col] = h0; dlo[o + col] = f2bu(v0 - bu2f(h0));
      float v1 = acc1[i]; u16 h1 = f2bu(v1);
      dhi[o + 16 + col] = h1; dlo[o + 16 + col] = f2bu(v1 - bu2f(h1));
    } else {
      dst[o + col] = acc0[i];
      dst[o + 16 + col] = acc1[i];
    }
  }
}

// ---------------------------------------------------------------- logits via MFMA: S=q·k^T/16, lrelu, R-mix, mask -> M
// Grid 1024 = b(4) x tb(16) x lb(16), lb fastest (k-slice L2 locality).
// 64 t-cols per block -> 4 blocks/CU (was 2): 50% occupancy for latency hiding.
__global__ __launch_bounds__(256) void k_logits_mfma(
    const u16* __restrict__ qh, const u16* __restrict__ ql,
    const u16* __restrict__ kh, const u16* __restrict__ kl,
    const float* __restrict__ Rm, const u32* __restrict__ bits,
    float* __restrict__ M) {
  __shared__ float Rlds[8][8];
  __shared__ float mtile[4][16 * 17];
  int tid = threadIdx.x, bid = blockIdx.x;
  int lb = bid & 15, tb = (bid >> 4) & 15, b = bid >> 8;   // lb fastest
  int wave = tid >> 6, lane = tid & 63;
  int l0 = (lb << 6) + (wave << 4);
  int tbase = tb << 6;
  int idx16 = lane & 15, g = lane >> 4;
  if (tid < 64) Rlds[tid >> 3][tid & 7] = Rm[tid];
  bf16x8 qfh[8], qfl[8];
#pragma unroll
  for (int h = 0; h < 8; ++h) {
    size_t off = ((size_t)(b * HH + h) * LL + l0 + idx16) * DD + (g << 3);
    qfh[h] = *(const bf16x8*)(qh + off);
    qfl[h] = *(const bf16x8*)(ql + off);
  }
  __syncthreads();
  int rr_ = lane >> 2, c0 = (lane & 3) << 2;   // LDS-read / global-write mapping
  for (int tt = 0; tt < 4; ++tt) {
    int t = tbase + (tt << 4);
    f32x4 S[8];
#pragma unroll
    for (int h = 0; h < 8; ++h) {
      size_t koff = ((size_t)(b * HH + h) * LL + t + idx16) * DD + (g << 3);
      bf16x8 bh_ = *(const bf16x8*)(kh + koff);
      bf16x8 bl_ = *(const bf16x8*)(kl + koff);
      f32x4 s = {0.f, 0.f, 0.f, 0.f};
      s = __builtin_amdgcn_mfma_f32_16x16x32_bf16(qfh[h], bh_, s, 0, 0, 0);
      s = __builtin_amdgcn_mfma_f32_16x16x32_bf16(qfl[h], bh_, s, 0, 0, 0);
      s = __builtin_amdgcn_mfma_f32_16x16x32_bf16(qfh[h], bl_, s, 0, 0, 0);
      S[h] = s;
    }
#pragma unroll
    for (int h = 0; h < 8; ++h)
#pragma unroll
      for (int e = 0; e < 4; ++e) {
        float v = S[h][e] * 0.0625f;
        S[h][e] = (v > 0.f) ? v : 0.01f * v;
      }
    int word = t >> 5;                 // idx16<16 never crosses a 32-bit word
    int bitpos = ((tt & 1) << 4) + idx16;
#pragma unroll
    for (int i = 0; i < 8; ++i) {
      float rr8[8];
#pragma unroll
      for (int h = 0; h < 8; ++h) rr8[h] = Rlds[i][h];
      const u32* bp = bits + ((size_t)(b * HH + i) * 32 + word) * LL + l0 + (g << 2);
      u32 mw0 = bp[0], mw1 = bp[1], mw2 = bp[2], mw3 = bp[3];
      float m_[4];
#pragma unroll
      for (int e = 0; e < 4; ++e) {
        float acc = 0.f;
#pragma unroll
        for (int h = 0; h < 8; ++h) acc += rr8[h] * S[h][e];
        u32 mw = (e == 0) ? mw0 : (e == 1) ? mw1 : (e == 2) ? mw2 : mw3;
        m_[e] = ((mw >> bitpos) & 1u) ? acc : -INFINITY;
      }
#pragma unroll
      for (int e = 0; e < 4; ++e)
        mtile[wave][((g << 2) + e) * 17 + idx16] = m_[e];
      float4 v4;
      v4.x = mtile[wave][rr_ * 17 + c0 + 0];
      v4.y = mtile[wave][rr_ * 17 + c0 + 1];
      v4.z = mtile[wave][rr_ * 17 + c0 + 2];
      v4.w = mtile[wave][rr_ * 17 + c0 + 3];
      *(float4*)(M + ((size_t)(b * HH + i) * LL + l0 + rr_) * LL + t + c0) = v4;
    }
  }
}

// ---------------------------------------------------------------- row softmax M->A in place + colpart + FUSED vb GEMM
__global__ __launch_bounds__(256) void k_norm2v(
    float* __restrict__ A, const u16* __restrict__ xvT,
    float* __restrict__ colpart, float* __restrict__ vb) {
  __shared__ u16 Ast[32][1032];   // 66 KB; stride 1032 -> b128 frag reads 2-way max
  int tid = threadIdx.x, bid = blockIdx.x;   // grid 1024 = bh(32) x ch(32)
  int ch = bid & 31, bh = bid >> 5;
  int wave = tid >> 6, lane = tid & 63;
  float4 colA[4];
#pragma unroll
  for (int j = 0; j < 4; ++j) colA[j] = make_float4(0.f, 0.f, 0.f, 0.f);
  for (int rr = 0; rr < 8; ++rr) {
    int row = (rr << 2) + wave;                  // 0..31 within block
    int l = (ch << 5) + row;
    float4* Ap = (float4*)(A + ((size_t)bh * LL + l) * LL);
    float4 v[4];
#pragma unroll
    for (int j = 0; j < 4; ++j) v[j] = Ap[lane + (j << 6)];
    float mx = -INFINITY;
#pragma unroll
    for (int j = 0; j < 4; ++j)
      mx = fmaxf(mx, fmaxf(fmaxf(v[j].x, v[j].y), fmaxf(v[j].z, v[j].w)));
#pragma unroll
    for (int o = 32; o > 0; o >>= 1) mx = fmaxf(mx, __shfl_xor(mx, o, 64));
    float sm = 0.f;
#pragma unroll
    for (int j = 0; j < 4; ++j) {
      v[j].x = __expf(v[j].x - mx); v[j].y = __expf(v[j].y - mx);
      v[j].z = __expf(v[j].z - mx); v[j].w = __expf(v[j].w - mx);
      sm += v[j].x + v[j].y + v[j].z + v[j].w;
    }
#pragma unroll
    for (int o = 32; o > 0; o >>= 1) sm += __shfl_xor(sm, o, 64);
    float inv = 1.0f / sm;
#pragma unroll
    for (int j = 0; j < 4; ++j) {
      v[j].x *= inv; v[j].y *= inv; v[j].z *= inv; v[j].w *= inv;
      colA[j].x += __expf(v[j].x); colA[j].y += __expf(v[j].y);
      colA[j].z += __expf(v[j].z); colA[j].w += __expf(v[j].w);
      Ap[lane + (j << 6)] = v[j];
      int c4 = (lane + (j << 6)) << 2;
      *(short4*)&Ast[row][c4] =
          make_short4(f2bs(v[j].x), f2bs(v[j].y), f2bs(v[j].z), f2bs(v[j].w));
    }
  }
  __syncthreads();
  // GEMM: wave = (Mt, Nt); C-frag 16x16; K = 1024
  int idx16 = lane & 15, g = lane >> 4;
  int Mt = wave >> 1, Nt = wave & 1;
  f32x4 acc = {0.f, 0.f, 0.f, 0.f};
  const u16* bbase = xvT + ((size_t)bh * DD + Nt * 16 + idx16) * LL;
#pragma unroll 4
  for (int kc = 0; kc < 32; ++kc) {
    bf16x8 af = *(const bf16x8*)&Ast[(Mt << 4) + idx16][(kc << 5) + (g << 3)];
    bf16x8 bfr = *(const bf16x8*)(bbase + (kc << 5) + (g << 3));
    acc = __builtin_amdgcn_mfma_f32_16x16x32_bf16(af, bfr, acc, 0, 0, 0);
  }
#pragma unroll
  for (int e = 0; e < 4; ++e)
    vb[((size_t)bh * LL + (ch << 5) + (Mt << 4) + (g << 2) + e) * DD + Nt * 16 + idx16] = acc[e];
  __syncthreads();
  // colpart via reused LDS
  float* cf = (float*)&Ast[0][0];
#pragma unroll
  for (int j = 0; j < 4; ++j)
    *(float4*)&cf[wave * 1024 + (j << 8) + (lane << 2)] = colA[j];
  __syncthreads();
  float4 s = make_float4(0.f, 0.f, 0.f, 0.f);
#pragma unroll
  for (int w = 0; w < 4; ++w) {
    float4 t = *(const float4*)&cf[w * 1024 + (tid << 2)];
    s.x += t.x; s.y += t.y; s.z += t.z; s.w += t.w;
  }
  ((float4*)(colpart + ((size_t)bh * 32 + ch) * LL))[tid] = s;
}

// ---------------------------------------------------------------- Ar[t,l] = exp(A[l,t])/colsum[t] + FUSED vr GEMM
// colsum inline from colpart. (r10 single-buffer form — r12 dbuf regressed.)
__global__ __launch_bounds__(256) void k_arv(
    const float* __restrict__ A, const float* __restrict__ colpart,
    const u16* __restrict__ xvrT, float* __restrict__ Ar, float* __restrict__ vrb) {
  __shared__ float tile[64][65];
  int tid = threadIdx.x, bid = blockIdx.x;   // grid 512 = bh(32) x tix(16)
  int tix = bid & 15, bh = bid >> 4;
  int t0 = tix << 6;
  int c = tid & 63, w4 = tid >> 6;
  int idx16 = c & 15, g = (c >> 4) & 3;
  float cs = 0.f;
  {
    const float* cp = colpart + (size_t)bh * 32 * LL + t0 + c;
#pragma unroll
    for (int chk = 0; chk < 32; ++chk) cs += cp[chk * LL];
  }
  float invc = 1.0f / cs;
  f32x4 acc0 = {0.f, 0.f, 0.f, 0.f}, acc1 = {0.f, 0.f, 0.f, 0.f};
  for (int tiy = 0; tiy < 16; ++tiy) {
    int l0 = tiy << 6;
    const float* Ab = A + ((size_t)bh * LL + l0) * LL + t0;
#pragma unroll
    for (int rr = 0; rr < 16; ++rr) {
      int li = (rr << 2) + w4;
      tile[li][c] = __expf(Ab[(size_t)li * LL + c]) * invc;   // scaled by 1/colsum[t0+c]
    }
    __syncthreads();
    // Ar write (transposed, coalesced); tile[c][ti] carries 1/colsum[t0+ti]
    float* Arb = Ar + ((size_t)bh * LL + t0) * LL + l0;
#pragma unroll
    for (int rr = 0; rr < 16; ++rr) {
      int ti = (rr << 2) + w4;
      Arb[(size_t)ti * LL + c] = tile[c][ti];
    }
    // vr MFMA: A-op[m=t][k=l] from tile (scalar ds reads, 2-way banks)
#pragma unroll
    for (int kc = 0; kc < 2; ++kc) {
      bf16x8 af;
#pragma unroll
      for (int j = 0; j < 8; ++j)
        af[j] = f2bs(tile[(kc << 5) + (g << 3) + j][(w4 << 4) + idx16]);
      const u16* bp = xvrT + ((size_t)bh * DD + idx16) * LL + l0 + (kc << 5) + (g << 3);
      bf16x8 b0 = *(const bf16x8*)bp;
      bf16x8 b1 = *(const bf16x8*)(bp + 16 * LL);
      acc0 = __builtin_amdgcn_mfma_f32_16x16x32_bf16(af, b0, acc0, 0, 0, 0);
      acc1 = __builtin_amdgcn_mfma_f32_16x16x32_bf16(af, b1, acc1, 0, 0, 0);
    }
    __syncthreads();
  }
#pragma unroll
  for (int e = 0; e < 4; ++e) {
    size_t o = ((size_t)bh * LL + t0 + (w4 << 4) + (g << 2) + e) * DD;
    vrb[o + idx16] = acc0[e];
    vrb[o + 16 + idx16] = acc1[e];
  }
}

// ---------------------------------------------------------------- out = gelu(v_merged) @ Wp, 16 rows/block, both outputs
__global__ __launch_bounds__(256) void k_out2(
    const float* __restrict__ vb, const float* __restrict__ vrb,
    const float* __restrict__ Wp,
    float* __restrict__ out, float* __restrict__ outr) {
  __shared__ float g_s[16 * 256];
  __shared__ float wp_s[32 * 256];
  int tid = threadIdx.x, bid = blockIdx.x;   // grid 512 = sel(2) x b(4) x lt(64)
  int sel = bid >> 8;
  const float* vbuf = sel ? vrb : vb;
  float* o = sel ? outr : out;
  int b2 = bid & 255;
  int lt = b2 & 63, b = b2 >> 6;
  int l0 = lt << 4;
  int h = tid >> 5, dd = tid & 31;
#pragma unroll
  for (int r = 0; r < 16; ++r) {
    float v = vbuf[(((size_t)b * HH + h) * LL + l0 + r) * DD + dd];
    g_s[r * 256 + tid] = 0.5f * v * (1.0f + erff(v * 0.70710678118654752f));
  }
  float acc[16];
#pragma unroll
  for (int r = 0; r < 16; ++r) acc[r] = 0.f;
  for (int jc = 0; jc < 8; ++jc) {
    __syncthreads();
#pragma unroll
    for (int u = 0; u < 8; ++u) {
      int idx = tid + (u << 8);
      int j = idx >> 6, c4 = idx & 63;
      float4 v = *(const float4*)(Wp + (size_t)(jc * 32 + j) * DIMM + (c4 << 2));
      *(float4*)&wp_s[j * 256 + (c4 << 2)] = v;
    }
    __syncthreads();
#pragma unroll
    for (int j = 0; j < 32; ++j) {
      float wv = wp_s[j * 256 + tid];
      int jj = (jc << 5) + j;
#pragma unroll
      for (int r = 0; r < 16; ++r)
        acc[r] += g_s[r * 256 + jj] * wv;
    }
  }
#pragma unroll
  for (int r = 0; r < 16; ++r)
    o[((size_t)b * LL + l0 + r) * DIMM + tid] = acc[r];
}

extern "C" void kernel_launch(void* const* d_in, const int* in_sizes, int n_in,
                              void* d_out, int out_size, void* d_ws, size_t ws_size,
                              hipStream_t stream) {
  const float* x    = (const float*)d_in[0];
  const float* rx   = (const float*)d_in[1];
  const float* adj  = (const float*)d_in[2];
  const float* adjr = (const float*)d_in[3];
  const float* Wq   = (const float*)d_in[4];
  const float* Wk   = (const float*)d_in[5];
  const float* Wv   = (const float*)d_in[6];
  const float* Rm   = (const float*)d_in[7];
  const float* Wp   = (const float*)d_in[8];

  const size_t NE = (size_t)BB * HH * LL * DD;   // 1,048,576 (= B*L*DIM)

  float* out  = (float*)d_out;
  float* outr = out + NE;
  float* A    = outr + NE;
  float* Ar   = A + (size_t)BB * HH * LL * LL;

  // Ar region (33.5M floats, dead until k_arv rewrites all of it):
  u16* q_hi   = (u16*)(Ar);
  u16* q_lo   = q_hi + NE;
  u16* k_hi   = q_lo + NE;
  u16* k_lo   = k_hi + NE;
  u16* xqT_hi = k_lo + NE;
  u16* xqT_lo = xqT_hi + NE;
  u16* xkT_hi = xqT_lo + NE;
  u16* xkT_lo = xkT_hi + NE;                    // ends at Ar + 4*NE floats
  // out region: xvT hi (consumed by k_norm2v before k_out2 writes out)
  u16* xvT_hi  = (u16*)out;
  // outr region: xvrT hi (consumed by k_arv before k_out2 writes outr)
  u16* xvrT_hi = (u16*)outr;

  // d_ws: 16.3 MB (colpart here: k_arv reads it while writing the Ar region)
  float* wsf    = (float*)d_ws;
  float* vb     = wsf;                       // NE f32
  float* vrb    = wsf + NE;                  // NE f32
  float* colpart = wsf + 2 * NE;             // NE f32
  u32* adjbits  = (u32*)(wsf + 3 * NE);      // BH*32*1024 u32 = 4 MB

  k_proj<<<4096, 256, 0, stream>>>(x, rx, Wq, Wk, Wv,
                                   xqT_hi, xqT_lo, xkT_hi, xkT_lo,
                                   xvT_hi, xvrT_hi);
  k_wmat2<2,1,1><<<1024, 256, 0, stream>>>(adj, adjr,
                                           xqT_hi, xqT_lo, xkT_hi, xkT_lo,
                                           nullptr, nullptr,
                                           q_hi, q_lo, k_hi, k_lo, adjbits);
  k_logits_mfma<<<1024, 256, 0, stream>>>(q_hi, q_lo, k_hi, k_lo, Rm, adjbits, A);
  k_norm2v<<<1024, 256, 0, stream>>>(A, xvT_hi, colpart, vb);
  k_arv<<<512, 256, 0, stream>>>(A, colpart, xvrT_hi, Ar, vrb);
  k_out2<<<512, 256, 0, stream>>>(vb, vrb, Wp, out, outr);
}